// Round 1
// baseline (440.878 us; speedup 1.0000x reference)
//
#include <hip/hip_runtime.h>
#include <hip/hip_bf16.h>

#define V 3
#define N 4096
#define D 512
#define H 128
#define C 5
#define KS 2                    // split-K factor for k2 (was 4: halves pacc round-trip)
#define M2 64                   // rows per k2 block
#define M1 32                   // rows per k1 block
#define LOG2E 1.4426950408889634f

typedef short short8 __attribute__((ext_vector_type(8)));
typedef float floatx4 __attribute__((ext_vector_type(4)));
typedef int   intx4  __attribute__((ext_vector_type(4)));

__device__ __forceinline__ unsigned short f2bf(float f){
  __hip_bfloat16 h = __float2bfloat16(f);
  return *reinterpret_cast<unsigned short*>(&h);
}
// RNE pack of two non-NaN floats to packed bf16x2
__device__ __forceinline__ unsigned int pk_bf16(float a, float b){
  unsigned int ua = __float_as_uint(a), ub = __float_as_uint(b);
  ua += 0x7FFFu + ((ua >> 16) & 1u);
  ub += 0x7FFFu + ((ub >> 16) & 1u);
  return (ua >> 16) | (ub & 0xFFFF0000u);
}

// ---------------- K0: all weight transposes in ONE launch ----------------
// blocks 0..47:  gac_w/mlp_w -> wT[mat][v][col][k]   (K=D, kc 0..7)
// blocks 48..71: q/k/v/fc    -> wq4T[mat][v][col][k] (K=H, kc 0..1)
__global__ __launch_bounds__(256) void k0_all(
    const float* __restrict__ gw, const float* __restrict__ mw,
    const float* __restrict__ qw, const float* __restrict__ kw,
    const float* __restrict__ vw, const float* __restrict__ fw,
    unsigned short* __restrict__ wT, unsigned short* __restrict__ wq4T)
{
  const int b = blockIdx.x, t = threadIdx.x;
  __shared__ unsigned short tr[128*72];
  const float* src;
  unsigned short* dst0;
  int K, koff;
  if (b < 48){
    const int v = b % V, r = b / V, m = r & 1, kc = r >> 1;   // kc 0..7
    src  = (m ? mw : gw) + (size_t)v*D*H + (size_t)kc*64*H;
    dst0 = wT + ((size_t)m*V + v)*(size_t)H*D;
    K = D; koff = kc*64;
  } else {
    const int j = b - 48, v = j % V, r = j / V, m = r & 3, kc = r >> 2; // kc 0..1
    src  = (m==0?qw: m==1?kw: m==2?vw: fw) + (size_t)v*H*H + (size_t)kc*64*H;
    dst0 = wq4T + ((size_t)m*V + v)*(size_t)H*H;
    K = H; koff = kc*64;
  }
  for (int i = t; i < 64*128; i += 256){
    int kk = i >> 7, col = i & 127;
    tr[col*72 + kk] = f2bf(src[i]);
  }
  __syncthreads();
  const int col = t >> 1, half = t & 1;
  uint4* dst = (uint4*)(dst0 + (size_t)col*K + koff + half*32);
  const unsigned short* s = &tr[col*72 + half*32];
  dst[0] = *(const uint4*)(s);
  dst[1] = *(const uint4*)(s + 8);
  dst[2] = *(const uint4*)(s + 16);
  dst[3] = *(const uint4*)(s + 24);
}

// ---------------- K1: MFMA dual-GEMM h=data@gac_w, mlp=data@mlp_w (r11, proven) ----------------
__global__ __launch_bounds__(512) void k1_gemm(
    const float* __restrict__ data, const unsigned short* __restrict__ wT,
    const float* __restrict__ a1, const float* __restrict__ a2,
    unsigned short* __restrict__ hT, float* __restrict__ mlp_out,
    float* __restrict__ e1g, float* __restrict__ e2g)
{
  const int v = blockIdx.y;
  const int n0 = blockIdx.x * M1;
  const int t = threadIdx.x;
  const int w = t >> 6, l = t & 63;
  __shared__ __align__(16) unsigned short AT[2][16][64][8];
  __shared__ float epart[2][M1][4];
  unsigned short* hTile = &AT[0][0][0][0];

  {
    const int r = t >> 4, oct = t & 15;
    const float4* dp = (const float4*)(data + ((size_t)v*N + n0 + r)*D + oct*32);
    float4 f[8];
    #pragma unroll
    for (int i=0;i<8;i++) f[i] = dp[i];
    #pragma unroll
    for (int q=0;q<4;q++){
      uint4 u;
      u.x = pk_bf16(f[2*q].x,   f[2*q].y);
      u.y = pk_bf16(f[2*q].z,   f[2*q].w);
      u.z = pk_bf16(f[2*q+1].x, f[2*q+1].y);
      u.w = pk_bf16(f[2*q+1].z, f[2*q+1].w);
      *(uint4*)&AT[r>>4][oct][(r&15) + 16*q][0] = u;
    }
  }
  __syncthreads();
  const int m = w >> 2, cb = (w & 3)*32;
  const int quad = l >> 4, c16 = l & 15;
  const unsigned short* b0 = wT + (((size_t)m*V + v)*H + cb + c16)*D + quad*8;
  floatx4 acc[2][2];
  #pragma unroll
  for (int rt=0;rt<2;rt++) for (int c=0;c<2;c++) acc[rt][c] = (floatx4){0.f,0.f,0.f,0.f};
  #pragma unroll
  for (int ks=0; ks<16; ks++){
    short8 a0 = *(const short8*)&AT[0][ks][l][0];
    short8 a1f = *(const short8*)&AT[1][ks][l][0];
    short8 bb0 = *(const short8*)(b0 + ks*32);
    short8 bb1 = *(const short8*)(b0 + 16*D + ks*32);
    acc[0][0] = __builtin_amdgcn_mfma_f32_16x16x32_bf16(a0,  bb0, acc[0][0], 0,0,0);
    acc[1][0] = __builtin_amdgcn_mfma_f32_16x16x32_bf16(a1f, bb0, acc[1][0], 0,0,0);
    acc[0][1] = __builtin_amdgcn_mfma_f32_16x16x32_bf16(a0,  bb1, acc[0][1], 0,0,0);
    acc[1][1] = __builtin_amdgcn_mfma_f32_16x16x32_bf16(a1f, bb1, acc[1][1], 0,0,0);
  }
  if (m == 1){
    #pragma unroll
    for (int rt=0;rt<2;rt++)
      #pragma unroll
      for (int c=0;c<2;c++)
        #pragma unroll
        for (int reg=0;reg<4;reg++){
          const int row = rt*16 + quad*4 + reg, col = cb + c*16 + c16;
          mlp_out[((size_t)v*N + n0 + row)*H + col] = acc[rt][c][reg];
        }
  } else {
    const float a1v0 = a1[v*H + cb + c16],      a2v0 = a2[v*H + cb + c16];
    const float a1v1 = a1[v*H + cb + 16 + c16], a2v1 = a2[v*H + cb + 16 + c16];
    #pragma unroll
    for (int rt=0;rt<2;rt++)
      #pragma unroll
      for (int reg=0;reg<4;reg++){
        float p1 = acc[rt][0][reg]*a1v0 + acc[rt][1][reg]*a1v1;
        float p2 = acc[rt][0][reg]*a2v0 + acc[rt][1][reg]*a2v1;
        p1 += __shfl_xor(p1,1); p1 += __shfl_xor(p1,2);
        p1 += __shfl_xor(p1,4); p1 += __shfl_xor(p1,8);
        p2 += __shfl_xor(p2,1); p2 += __shfl_xor(p2,2);
        p2 += __shfl_xor(p2,4); p2 += __shfl_xor(p2,8);
        if (c16 == 0){
          epart[0][rt*16 + quad*4 + reg][w] = p1;
          epart[1][rt*16 + quad*4 + reg][w] = p2;
        }
      }
  }
  __syncthreads();
  if (m == 0){
    #pragma unroll
    for (int rt=0;rt<2;rt++)
      #pragma unroll
      for (int c=0;c<2;c++)
        #pragma unroll
        for (int reg=0;reg<4;reg++){
          const int row = rt*16 + quad*4 + reg, col = cb + c*16 + c16;
          hTile[col*40 + row] = f2bf(acc[rt][c][reg]);
        }
  }
  __syncthreads();
  if (t < 128){
    const unsigned short* s = &hTile[t*40];
    uint4* dst = (uint4*)(hT + ((size_t)v*H + t)*N + n0);
    dst[0] = *(const uint4*)(s);
    dst[1] = *(const uint4*)(s + 8);
    dst[2] = *(const uint4*)(s + 16);
    dst[3] = *(const uint4*)(s + 24);
  } else if (t < 128 + M1){
    const int r = t - 128;
    e1g[(size_t)v*N + n0 + r] = LOG2E*(epart[0][r][0]+epart[0][r][1]+epart[0][r][2]+epart[0][r][3]);
  } else if (t < 128 + 2*M1){
    const int r = t - 128 - M1;
    e2g[(size_t)v*N + n0 + r] = LOG2E*(epart[1][r][0]+epart[1][r][1]+epart[1][r][2]+epart[1][r][3]);
  }
}

// ---------------- K2: masked graph attention via bf16 MFMA (r10, proven; KS=2) ----------------
__global__ __launch_bounds__(512, 4) void k2_attn(
    const unsigned short* __restrict__ hT, const int* __restrict__ adj,
    const float* __restrict__ e1g, const float* __restrict__ e2g,
    float* __restrict__ pacc, float* __restrict__ pdenG)
{
  const int v = blockIdx.z;
  const int ksid = blockIdx.y;
  const int n0 = blockIdx.x * M2;
  const int kbase = ksid * (N/KS);
  const int t = threadIdx.x;
  const int w = t >> 6, l = t & 63;
  __shared__ __align__(16) unsigned short Afrag[2][4][4][64][8];
  __shared__ float pden_sh[M2][4];

  const int ksl  = w & 3;
  const int quad = l >> 4;
  const int rt0  = w >> 2;
  const int row0 = rt0*16 + (l & 15);
  const int row1 = row0 + 32;
  const int koff = ksl*32 + quad*8;
  const intx4* ap0 = (const intx4*)(adj + ((size_t)v*N + n0 + row0)*N + kbase + koff);
  const intx4* ap1 = (const intx4*)(adj + ((size_t)v*N + n0 + row1)*N + kbase + koff);
  const float4* ep = (const float4*)(e2g + (size_t)v*N + kbase + koff);
  const float e1r0 = e1g[(size_t)v*N + n0 + row0];
  const float e1r1 = e1g[(size_t)v*N + n0 + row1];
  float psum0 = 0.f, psum1 = 0.f;

  const int col = w*16 + (l & 15);
  const unsigned short* bcol = hT + ((size_t)v*H + col)*N + kbase + quad*8;
  floatx4 acc[4];
  #pragma unroll
  for (int rt=0;rt<4;rt++) acc[rt] = (floatx4){0.f,0.f,0.f,0.f};

  intx4  a00 = __builtin_nontemporal_load(ap0);
  intx4  a01 = __builtin_nontemporal_load(ap0 + 1);
  intx4  a10 = __builtin_nontemporal_load(ap1);
  intx4  a11 = __builtin_nontemporal_load(ap1 + 1);
  float4 ev0 = ep[0];
  float4 ev1 = ep[1];

  const int NCH = (N/KS)/128;
  #pragma unroll 1
  for (int c = 0; c < NCH; c++){
    const int buf = c & 1;
    {
      float ev[8] = {ev0.x,ev0.y,ev0.z,ev0.w, ev1.x,ev1.y,ev1.z,ev1.w};
      int   aa[8] = {a00.x,a00.y,a00.z,a00.w, a01.x,a01.y,a01.z,a01.w};
      int   bb[8] = {a10.x,a10.y,a10.z,a10.w, a11.x,a11.y,a11.z,a11.w};
      float wa[8], wb[8];
      #pragma unroll
      for (int j=0;j<8;j++){
        float ya = e1r0 + ev[j];
        ya = fmaxf(ya, 0.25f*ya);
        float ea = exp2f(ya);
        wa[j] = (aa[j] > 0) ? ea : 0.f;
        psum0 += wa[j];
        float yb = e1r1 + ev[j];
        yb = fmaxf(yb, 0.25f*yb);
        float eb = exp2f(yb);
        wb[j] = (bb[j] > 0) ? eb : 0.f;
        psum1 += wb[j];
      }
      union { short8 s; unsigned int u[4]; } pa, pb;
      #pragma unroll
      for (int j=0;j<4;j++){
        pa.u[j] = pk_bf16(wa[2*j], wa[2*j+1]);
        pb.u[j] = pk_bf16(wb[2*j], wb[2*j+1]);
      }
      *(short8*)&Afrag[buf][rt0  ][ksl][l][0] = pa.s;
      *(short8*)&Afrag[buf][rt0+2][ksl][l][0] = pb.s;
    }
    if (c+1 < NCH){
      a00 = __builtin_nontemporal_load(ap0 + (c+1)*32);
      a01 = __builtin_nontemporal_load(ap0 + (c+1)*32 + 1);
      a10 = __builtin_nontemporal_load(ap1 + (c+1)*32);
      a11 = __builtin_nontemporal_load(ap1 + (c+1)*32 + 1);
      ev0 = ep[(c+1)*32];
      ev1 = ep[(c+1)*32 + 1];
    }
    __syncthreads();
    #pragma unroll
    for (int ks=0; ks<4; ks++){
      short8 b8 = *(const short8*)(bcol + c*128 + ks*32);
      #pragma unroll
      for (int rt=0; rt<4; rt++){
        short8 a8 = *(const short8*)&Afrag[buf][rt][ks][l][0];
        acc[rt] = __builtin_amdgcn_mfma_f32_16x16x32_bf16(a8, b8, acc[rt], 0, 0, 0);
      }
    }
    __syncthreads();
  }
  psum0 += __shfl_xor(psum0, 16);
  psum0 += __shfl_xor(psum0, 32);
  psum1 += __shfl_xor(psum1, 16);
  psum1 += __shfl_xor(psum1, 32);
  if (l < 16){
    pden_sh[row0][ksl] = psum0;
    pden_sh[row1][ksl] = psum1;
  }
  __syncthreads();
  const size_t pb = ((size_t)v*KS + ksid)*(N/M2) + blockIdx.x;
  float* pa = pacc + pb*(M2*H);
  #pragma unroll
  for (int rt=0; rt<4; rt++){
    #pragma unroll
    for (int reg=0; reg<4; reg++){
      const int row = rt*16 + quad*4 + reg;
      pa[row*H + col] = acc[rt][reg];
    }
  }
  if (t < M2){
    float den = pden_sh[t][0] + pden_sh[t][1] + pden_sh[t][2] + pden_sh[t][3];
    pdenG[pb*M2 + t] = den;
  }
}

// ---------------- K3: fused combine+epilogue, MFMA QKV, VALU attention, MFMA fc ----------------
// 16 nodes/block, 256 thr (4 waves). Q stored pre-scaled by invs*log2e so the
// attention inner loop is 1 mul + 1 exp2 per element (was 2 mul + 1 exp).
__global__ __launch_bounds__(256) void k3_sgfe(
    const float* __restrict__ pacc, const float* __restrict__ pdenG,
    const float* __restrict__ mlp_out,
    const float* __restrict__ gac_b, const float* __restrict__ mlp_b,
    const unsigned short* __restrict__ wq4T,
    const float* __restrict__ qb, const float* __restrict__ kb,
    const float* __restrict__ vb, const float* __restrict__ fcb,
    const float* __restrict__ confw, const float* __restrict__ confb,
    float* __restrict__ feat2)
{
  const int v = blockIdx.y;
  const int n0 = blockIdx.x * 16;
  const int t = threadIdx.x;
  const int w = t >> 6, l = t & 63;
  const int c16 = l & 15, quad = l >> 4;
  __shared__ __align__(16) unsigned short Ffrag[4][64][8];   // feat A-fragments
  __shared__ __align__(16) unsigned short Gfrag[4][64][8];   // agg A-fragments
  __shared__ float Qs[16][H];
  __shared__ float2 KVs[16][H];
  __shared__ float pc[16][4];
  __shared__ float confs[16];

  // ---- fused split-K combine + GAC epilogue -> bf16 F fragments ----
  {
    const int col = t & 127, rh = t >> 7;
    const int bx2 = blockIdx.x >> 2;
    const int lr0 = (blockIdx.x & 3) * 16;
    const float gbv = gac_b[v*H + col];
    const float mbv = mlp_b[v*H + col];
    const int ks = col >> 5, q2 = (col & 31) >> 3, j = col & 7;
    #pragma unroll
    for (int i=0;i<8;i++){
      const int r = rh*8 + i;
      float num = 0.f, den = 0.f;
      #pragma unroll
      for (int s=0;s<KS;s++){
        const size_t pb = ((size_t)v*KS + s)*(N/M2) + bx2;
        num += pacc[pb*(M2*H) + (size_t)(lr0+r)*H + col];
        den += pdenG[pb*M2 + lr0 + r];
      }
      float x = num/den + gbv;
      x = (x >= 0.f) ? x : 0.25f*x;
      x += mlp_out[((size_t)v*N + n0 + r)*H + col] + mbv;
      Ffrag[ks][r + 16*q2][j] = f2bf(x);
    }
  }
  __syncthreads();
  // ---- QKV MFMA: wave w covers col-tiles {2w, 2w+1} for q,k,v ----
  const int colw0 = 2*w*16 + c16;
  const float QSC = 0.08838834764831845f * LOG2E;  // (1/sqrt(128)) * log2(e)
  {
    const unsigned short* bq = wq4T + (((size_t)0*V + v)*H + colw0)*H + quad*8;
    const unsigned short* bk = wq4T + (((size_t)1*V + v)*H + colw0)*H + quad*8;
    const unsigned short* bv = wq4T + (((size_t)2*V + v)*H + colw0)*H + quad*8;
    floatx4 aq[2], ak[2], av[2];
    #pragma unroll
    for (int c=0;c<2;c++){ aq[c]=(floatx4){0,0,0,0}; ak[c]=(floatx4){0,0,0,0}; av[c]=(floatx4){0,0,0,0}; }
    #pragma unroll
    for (int ks=0; ks<4; ks++){
      short8 a8 = *(const short8*)&Ffrag[ks][l][0];
      #pragma unroll
      for (int c=0;c<2;c++){
        short8 q8 = *(const short8*)(bq + (size_t)c*16*H + ks*32);
        short8 k8 = *(const short8*)(bk + (size_t)c*16*H + ks*32);
        short8 v8 = *(const short8*)(bv + (size_t)c*16*H + ks*32);
        aq[c] = __builtin_amdgcn_mfma_f32_16x16x32_bf16(a8, q8, aq[c], 0,0,0);
        ak[c] = __builtin_amdgcn_mfma_f32_16x16x32_bf16(a8, k8, ak[c], 0,0,0);
        av[c] = __builtin_amdgcn_mfma_f32_16x16x32_bf16(a8, v8, av[c], 0,0,0);
      }
    }
    #pragma unroll
    for (int c=0;c<2;c++){
      const int col = colw0 + c*16;
      const float qbv = qb[v*H+col], kbv = kb[v*H+col], vbv = vb[v*H+col];
      #pragma unroll
      for (int reg=0;reg<4;reg++){
        const int node = quad*4 + reg;
        Qs[node][col] = (aq[c][reg] + qbv) * QSC;
        KVs[node][col] = make_float2(ak[c][reg] + kbv, av[c][reg] + vbv);
      }
    }
  }
  __syncthreads();
  // ---- attention (VALU): wave w -> nodes 4w..4w+3; lane covers dims l, l+64 ----
  #pragma unroll
  for (int p=0;p<4;p++){
    const int r = 4*w + p;
    const float qa  = Qs[r][l];
    const float qb2 = Qs[r][l+64];
    float sA=0.f, aA=0.f, sB=0.f, aB=0.f;
    const float4* kvp = (const float4*)&KVs[r][0];
    #pragma unroll 4
    for (int oo=0; oo<H/2; oo++){
      float4 kv2 = kvp[oo];
      float eA0 = exp2f(qa*kv2.x);  sA += eA0; aA = fmaf(eA0, kv2.y, aA);
      float eA1 = exp2f(qa*kv2.z);  sA += eA1; aA = fmaf(eA1, kv2.w, aA);
      float eB0 = exp2f(qb2*kv2.x); sB += eB0; aB = fmaf(eB0, kv2.y, aB);
      float eB1 = exp2f(qb2*kv2.z); sB += eB1; aB = fmaf(eB1, kv2.w, aB);
    }
    // write agg into fc A-fragments (dims l and l+64)
    Gfrag[l>>5][r + 16*((l&31)>>3)][l&7] = f2bf(aA/sA);
    Gfrag[2 + (l>>5)][r + 16*((l&31)>>3)][l&7] = f2bf(aB/sB);
  }
  __syncthreads();
  // ---- fc MFMA + relu + conf gate ----
  const unsigned short* bf = wq4T + (((size_t)3*V + v)*H + colw0)*H + quad*8;
  floatx4 af[2];
  af[0]=(floatx4){0,0,0,0}; af[1]=(floatx4){0,0,0,0};
  #pragma unroll
  for (int ks=0; ks<4; ks++){
    short8 a8 = *(const short8*)&Gfrag[ks][l][0];
    #pragma unroll
    for (int c=0;c<2;c++){
      short8 b8 = *(const short8*)(bf + (size_t)c*16*H + ks*32);
      af[c] = __builtin_amdgcn_mfma_f32_16x16x32_bf16(a8, b8, af[c], 0,0,0);
    }
  }
  float g[2][4];
  float pn[4] = {0.f,0.f,0.f,0.f};
  #pragma unroll
  for (int c=0;c<2;c++){
    const int col = colw0 + c*16;
    const float fcbv = fcb[v*H+col];
    const float cwv  = confw[v*H+col];
    #pragma unroll
    for (int reg=0;reg<4;reg++){
      float gg = fmaxf(af[c][reg] + fcbv, 0.f);
      g[c][reg] = gg;
      pn[reg] += gg*cwv;
    }
  }
  #pragma unroll
  for (int reg=0;reg<4;reg++){
    pn[reg] += __shfl_xor(pn[reg], 1);
    pn[reg] += __shfl_xor(pn[reg], 2);
    pn[reg] += __shfl_xor(pn[reg], 4);
    pn[reg] += __shfl_xor(pn[reg], 8);
  }
  if (c16 == 0){
    #pragma unroll
    for (int reg=0;reg<4;reg++) pc[quad*4 + reg][w] = pn[reg];
  }
  __syncthreads();
  if (t < 16) confs[t] = pc[t][0] + pc[t][1] + pc[t][2] + pc[t][3] + confb[v];
  __syncthreads();
  #pragma unroll
  for (int c=0;c<2;c++){
    const int col = colw0 + c*16;
    #pragma unroll
    for (int reg=0;reg<4;reg++){
      const int node = quad*4 + reg;
      feat2[((size_t)v*N + n0 + node)*H + col] = g[c][reg]*confs[node];
    }
  }
}

// ---------------- K4: final classifier [N, V*H] @ [V*H, C], 4 nodes/block ----------------
__global__ __launch_bounds__(256) void k4_cls(
    const float* __restrict__ feat2,
    const float* __restrict__ mm_w, const float* __restrict__ mm_b,
    float* __restrict__ out)
{
  const int n = blockIdx.x*4 + (threadIdx.x >> 6);
  const int t = threadIdx.x & 63;
  float a[C] = {0,0,0,0,0};
  for (int j=t; j<V*H; j+=64){
    int vv = j >> 7, hh = j & (H-1);
    float f = feat2[((size_t)vv*N + n)*H + hh];
    #pragma unroll
    for (int c=0;c<C;c++) a[c] = fmaf(f, mm_w[j*C+c], a[c]);
  }
  #pragma unroll
  for (int c=0;c<C;c++){
    #pragma unroll
    for (int o=32;o>0;o>>=1) a[c] += __shfl_down(a[c],o);
  }
  if (t==0){
    #pragma unroll
    for (int c=0;c<C;c++) out[(size_t)n*C+c] = a[c] + mm_b[c];
  }
}

extern "C" void kernel_launch(void* const* d_in, const int* in_sizes, int n_in,
                              void* d_out, int out_size, void* d_ws, size_t ws_size,
                              hipStream_t stream)
{
  (void)in_sizes; (void)n_in; (void)out_size; (void)ws_size;
  const float* data  = (const float*)d_in[0];
  const int*   adj   = (const int*)d_in[1];
  const float* gac_w = (const float*)d_in[2];
  const float* gac_b = (const float*)d_in[3];
  const float* a1    = (const float*)d_in[4];
  const float* a2    = (const float*)d_in[5];
  const float* mlp_w = (const float*)d_in[6];
  const float* mlp_b = (const float*)d_in[7];
  const float* q_w   = (const float*)d_in[8];
  const float* q_b   = (const float*)d_in[9];
  const float* k_w   = (const float*)d_in[10];
  const float* k_b   = (const float*)d_in[11];
  const float* v_w   = (const float*)d_in[12];
  const float* v_b   = (const float*)d_in[13];
  const float* fc_w  = (const float*)d_in[14];
  const float* fc_b  = (const float*)d_in[15];
  const float* cw    = (const float*)d_in[16];
  const float* cb    = (const float*)d_in[17];
  const float* mm_w  = (const float*)d_in[18];
  const float* mm_b  = (const float*)d_in[19];

  float* ws = (float*)d_ws;
  const size_t VNH = (size_t)V*N*H;
  float* mlp   = ws;
  float* feat2 = ws + VNH;
  float* e1    = ws + 2*VNH;
  float* e2    = e1 + (size_t)V*N;
  unsigned short* hT   = (unsigned short*)(e2 + (size_t)V*N); // [V][H][N] bf16
  unsigned short* wT   = hT + VNH;                            // [2][V][H][D] bf16
  unsigned short* wq4T = wT + (size_t)2*V*H*D;                // [4][V][H][H] bf16
  float* pacc  = (float*)(wq4T + (size_t)4*V*H*H);            // [V][KS][N/M2][M2][H]
  float* pden  = pacc + (size_t)V*KS*(N/M2)*M2*H;             // [V][KS][N/M2][M2]

  k0_all <<<dim3(72),          256, 0, stream>>>(gac_w, mlp_w, q_w, k_w, v_w, fc_w, wT, wq4T);
  k1_gemm<<<dim3(N/M1, V),     512, 0, stream>>>(data, wT, a1, a2, hT, mlp, e1, e2);
  k2_attn<<<dim3(N/M2, KS, V), 512, 0, stream>>>(hT, adj, e1, e2, pacc, pden);
  k3_sgfe<<<dim3(N/16, V),     256, 0, stream>>>(pacc, pden, mlp, gac_b, mlp_b,
                                                 wq4T, q_b, k_b, v_b, fc_b,
                                                 cw, cb, feat2);
  k4_cls <<<dim3(N/4),         256, 0, stream>>>(feat2, mm_w, mm_b, (float*)d_out);
}

// Round 2
// 437.097 us; speedup vs baseline: 1.0087x; 1.0087x over previous
//
#include <hip/hip_runtime.h>
#include <hip/hip_bf16.h>

#define V 3
#define N 4096
#define D 512
#define H 128
#define C 5
#define KS 4                    // split-K factor for k2 (768 blocks = 3/CU, balanced)
#define M2 64                   // rows per k2 block
#define M1 32                   // rows per k1 block
#define LOG2E 1.4426950408889634f

typedef short short8 __attribute__((ext_vector_type(8)));
typedef float floatx4 __attribute__((ext_vector_type(4)));
typedef int   intx4  __attribute__((ext_vector_type(4)));

__device__ __forceinline__ unsigned short f2bf(float f){
  __hip_bfloat16 h = __float2bfloat16(f);
  return *reinterpret_cast<unsigned short*>(&h);
}
// RNE pack of two non-NaN floats to packed bf16x2
__device__ __forceinline__ unsigned int pk_bf16(float a, float b){
  unsigned int ua = __float_as_uint(a), ub = __float_as_uint(b);
  ua += 0x7FFFu + ((ua >> 16) & 1u);
  ub += 0x7FFFu + ((ub >> 16) & 1u);
  return (ua >> 16) | (ub & 0xFFFF0000u);
}

// ---------------- K0: all weight transposes in ONE launch ----------------
// blocks 0..47:  gac_w/mlp_w -> wT[mat][v][col][k]   (K=D, kc 0..7)
// blocks 48..71: q/k/v/fc    -> wq4T[mat][v][col][k] (K=H, kc 0..1)
__global__ __launch_bounds__(256) void k0_all(
    const float* __restrict__ gw, const float* __restrict__ mw,
    const float* __restrict__ qw, const float* __restrict__ kw,
    const float* __restrict__ vw, const float* __restrict__ fw,
    unsigned short* __restrict__ wT, unsigned short* __restrict__ wq4T)
{
  const int b = blockIdx.x, t = threadIdx.x;
  __shared__ unsigned short tr[128*72];
  const float* src;
  unsigned short* dst0;
  int K, koff;
  if (b < 48){
    const int v = b % V, r = b / V, m = r & 1, kc = r >> 1;   // kc 0..7
    src  = (m ? mw : gw) + (size_t)v*D*H + (size_t)kc*64*H;
    dst0 = wT + ((size_t)m*V + v)*(size_t)H*D;
    K = D; koff = kc*64;
  } else {
    const int j = b - 48, v = j % V, r = j / V, m = r & 3, kc = r >> 2; // kc 0..1
    src  = (m==0?qw: m==1?kw: m==2?vw: fw) + (size_t)v*H*H + (size_t)kc*64*H;
    dst0 = wq4T + ((size_t)m*V + v)*(size_t)H*H;
    K = H; koff = kc*64;
  }
  for (int i = t; i < 64*128; i += 256){
    int kk = i >> 7, col = i & 127;
    tr[col*72 + kk] = f2bf(src[i]);
  }
  __syncthreads();
  const int col = t >> 1, half = t & 1;
  uint4* dst = (uint4*)(dst0 + (size_t)col*K + koff + half*32);
  const unsigned short* s = &tr[col*72 + half*32];
  dst[0] = *(const uint4*)(s);
  dst[1] = *(const uint4*)(s + 8);
  dst[2] = *(const uint4*)(s + 16);
  dst[3] = *(const uint4*)(s + 24);
}

// ---------------- K1: MFMA dual-GEMM h=data@gac_w, mlp=data@mlp_w (proven) ----------------
__global__ __launch_bounds__(512) void k1_gemm(
    const float* __restrict__ data, const unsigned short* __restrict__ wT,
    const float* __restrict__ a1, const float* __restrict__ a2,
    unsigned short* __restrict__ hT, float* __restrict__ mlp_out,
    float* __restrict__ e1g, float* __restrict__ e2g)
{
  const int v = blockIdx.y;
  const int n0 = blockIdx.x * M1;
  const int t = threadIdx.x;
  const int w = t >> 6, l = t & 63;
  __shared__ __align__(16) unsigned short AT[2][16][64][8];
  __shared__ float epart[2][M1][4];
  unsigned short* hTile = &AT[0][0][0][0];

  {
    const int r = t >> 4, oct = t & 15;
    const float4* dp = (const float4*)(data + ((size_t)v*N + n0 + r)*D + oct*32);
    float4 f[8];
    #pragma unroll
    for (int i=0;i<8;i++) f[i] = dp[i];
    #pragma unroll
    for (int q=0;q<4;q++){
      uint4 u;
      u.x = pk_bf16(f[2*q].x,   f[2*q].y);
      u.y = pk_bf16(f[2*q].z,   f[2*q].w);
      u.z = pk_bf16(f[2*q+1].x, f[2*q+1].y);
      u.w = pk_bf16(f[2*q+1].z, f[2*q+1].w);
      *(uint4*)&AT[r>>4][oct][(r&15) + 16*q][0] = u;
    }
  }
  __syncthreads();
  const int m = w >> 2, cb = (w & 3)*32;
  const int quad = l >> 4, c16 = l & 15;
  const unsigned short* b0 = wT + (((size_t)m*V + v)*H + cb + c16)*D + quad*8;
  floatx4 acc[2][2];
  #pragma unroll
  for (int rt=0;rt<2;rt++) for (int c=0;c<2;c++) acc[rt][c] = (floatx4){0.f,0.f,0.f,0.f};
  #pragma unroll
  for (int ks=0; ks<16; ks++){
    short8 a0 = *(const short8*)&AT[0][ks][l][0];
    short8 a1f = *(const short8*)&AT[1][ks][l][0];
    short8 bb0 = *(const short8*)(b0 + ks*32);
    short8 bb1 = *(const short8*)(b0 + 16*D + ks*32);
    acc[0][0] = __builtin_amdgcn_mfma_f32_16x16x32_bf16(a0,  bb0, acc[0][0], 0,0,0);
    acc[1][0] = __builtin_amdgcn_mfma_f32_16x16x32_bf16(a1f, bb0, acc[1][0], 0,0,0);
    acc[0][1] = __builtin_amdgcn_mfma_f32_16x16x32_bf16(a0,  bb1, acc[0][1], 0,0,0);
    acc[1][1] = __builtin_amdgcn_mfma_f32_16x16x32_bf16(a1f, bb1, acc[1][1], 0,0,0);
  }
  if (m == 1){
    #pragma unroll
    for (int rt=0;rt<2;rt++)
      #pragma unroll
      for (int c=0;c<2;c++)
        #pragma unroll
        for (int reg=0;reg<4;reg++){
          const int row = rt*16 + quad*4 + reg, col = cb + c*16 + c16;
          mlp_out[((size_t)v*N + n0 + row)*H + col] = acc[rt][c][reg];
        }
  } else {
    const float a1v0 = a1[v*H + cb + c16],      a2v0 = a2[v*H + cb + c16];
    const float a1v1 = a1[v*H + cb + 16 + c16], a2v1 = a2[v*H + cb + 16 + c16];
    #pragma unroll
    for (int rt=0;rt<2;rt++)
      #pragma unroll
      for (int reg=0;reg<4;reg++){
        float p1 = acc[rt][0][reg]*a1v0 + acc[rt][1][reg]*a1v1;
        float p2 = acc[rt][0][reg]*a2v0 + acc[rt][1][reg]*a2v1;
        p1 += __shfl_xor(p1,1); p1 += __shfl_xor(p1,2);
        p1 += __shfl_xor(p1,4); p1 += __shfl_xor(p1,8);
        p2 += __shfl_xor(p2,1); p2 += __shfl_xor(p2,2);
        p2 += __shfl_xor(p2,4); p2 += __shfl_xor(p2,8);
        if (c16 == 0){
          epart[0][rt*16 + quad*4 + reg][w] = p1;
          epart[1][rt*16 + quad*4 + reg][w] = p2;
        }
      }
  }
  __syncthreads();
  if (m == 0){
    #pragma unroll
    for (int rt=0;rt<2;rt++)
      #pragma unroll
      for (int c=0;c<2;c++)
        #pragma unroll
        for (int reg=0;reg<4;reg++){
          const int row = rt*16 + quad*4 + reg, col = cb + c*16 + c16;
          hTile[col*40 + row] = f2bf(acc[rt][c][reg]);
        }
  }
  __syncthreads();
  if (t < 128){
    const unsigned short* s = &hTile[t*40];
    uint4* dst = (uint4*)(hT + ((size_t)v*H + t)*N + n0);
    dst[0] = *(const uint4*)(s);
    dst[1] = *(const uint4*)(s + 8);
    dst[2] = *(const uint4*)(s + 16);
    dst[3] = *(const uint4*)(s + 24);
  } else if (t < 128 + M1){
    const int r = t - 128;
    e1g[(size_t)v*N + n0 + r] = LOG2E*(epart[0][r][0]+epart[0][r][1]+epart[0][r][2]+epart[0][r][3]);
  } else if (t < 128 + 2*M1){
    const int r = t - 128 - M1;
    e2g[(size_t)v*N + n0 + r] = LOG2E*(epart[1][r][0]+epart[1][r][1]+epart[1][r][2]+epart[1][r][3]);
  }
}

// ---------------- K2: masked graph attention via bf16 MFMA (KS=4, proven) ----------------
// Tail: blocks (y==0,z==0) init out = mm_b for K3's atomic classifier.
__global__ __launch_bounds__(512, 4) void k2_attn(
    const unsigned short* __restrict__ hT, const int* __restrict__ adj,
    const float* __restrict__ e1g, const float* __restrict__ e2g,
    float* __restrict__ pacc, float* __restrict__ pdenG,
    const float* __restrict__ mm_b, float* __restrict__ outg)
{
  const int v = blockIdx.z;
  const int ksid = blockIdx.y;
  const int n0 = blockIdx.x * M2;
  const int kbase = ksid * (N/KS);
  const int t = threadIdx.x;
  const int w = t >> 6, l = t & 63;
  __shared__ __align__(16) unsigned short Afrag[2][4][4][64][8];
  __shared__ float pden_sh[M2][4];

  const int ksl  = w & 3;
  const int quad = l >> 4;
  const int rt0  = w >> 2;
  const int row0 = rt0*16 + (l & 15);
  const int row1 = row0 + 32;
  const int koff = ksl*32 + quad*8;
  const intx4* ap0 = (const intx4*)(adj + ((size_t)v*N + n0 + row0)*N + kbase + koff);
  const intx4* ap1 = (const intx4*)(adj + ((size_t)v*N + n0 + row1)*N + kbase + koff);
  const float4* ep = (const float4*)(e2g + (size_t)v*N + kbase + koff);
  const float e1r0 = e1g[(size_t)v*N + n0 + row0];
  const float e1r1 = e1g[(size_t)v*N + n0 + row1];
  float psum0 = 0.f, psum1 = 0.f;

  const int col = w*16 + (l & 15);
  const unsigned short* bcol = hT + ((size_t)v*H + col)*N + kbase + quad*8;
  floatx4 acc[4];
  #pragma unroll
  for (int rt=0;rt<4;rt++) acc[rt] = (floatx4){0.f,0.f,0.f,0.f};

  intx4  a00 = __builtin_nontemporal_load(ap0);
  intx4  a01 = __builtin_nontemporal_load(ap0 + 1);
  intx4  a10 = __builtin_nontemporal_load(ap1);
  intx4  a11 = __builtin_nontemporal_load(ap1 + 1);
  float4 ev0 = ep[0];
  float4 ev1 = ep[1];

  const int NCH = (N/KS)/128;
  #pragma unroll 1
  for (int c = 0; c < NCH; c++){
    const int buf = c & 1;
    {
      float ev[8] = {ev0.x,ev0.y,ev0.z,ev0.w, ev1.x,ev1.y,ev1.z,ev1.w};
      int   aa[8] = {a00.x,a00.y,a00.z,a00.w, a01.x,a01.y,a01.z,a01.w};
      int   bb[8] = {a10.x,a10.y,a10.z,a10.w, a11.x,a11.y,a11.z,a11.w};
      float wa[8], wb[8];
      #pragma unroll
      for (int j=0;j<8;j++){
        float ya = e1r0 + ev[j];
        ya = fmaxf(ya, 0.25f*ya);
        float ea = exp2f(ya);
        wa[j] = (aa[j] > 0) ? ea : 0.f;
        psum0 += wa[j];
        float yb = e1r1 + ev[j];
        yb = fmaxf(yb, 0.25f*yb);
        float eb = exp2f(yb);
        wb[j] = (bb[j] > 0) ? eb : 0.f;
        psum1 += wb[j];
      }
      union { short8 s; unsigned int u[4]; } pa, pb;
      #pragma unroll
      for (int j=0;j<4;j++){
        pa.u[j] = pk_bf16(wa[2*j], wa[2*j+1]);
        pb.u[j] = pk_bf16(wb[2*j], wb[2*j+1]);
      }
      *(short8*)&Afrag[buf][rt0  ][ksl][l][0] = pa.s;
      *(short8*)&Afrag[buf][rt0+2][ksl][l][0] = pb.s;
    }
    if (c+1 < NCH){
      a00 = __builtin_nontemporal_load(ap0 + (c+1)*32);
      a01 = __builtin_nontemporal_load(ap0 + (c+1)*32 + 1);
      a10 = __builtin_nontemporal_load(ap1 + (c+1)*32);
      a11 = __builtin_nontemporal_load(ap1 + (c+1)*32 + 1);
      ev0 = ep[(c+1)*32];
      ev1 = ep[(c+1)*32 + 1];
    }
    __syncthreads();
    #pragma unroll
    for (int ks=0; ks<4; ks++){
      short8 b8 = *(const short8*)(bcol + c*128 + ks*32);
      #pragma unroll
      for (int rt=0; rt<4; rt++){
        short8 a8 = *(const short8*)&Afrag[buf][rt][ks][l][0];
        acc[rt] = __builtin_amdgcn_mfma_f32_16x16x32_bf16(a8, b8, acc[rt], 0, 0, 0);
      }
    }
    __syncthreads();
  }
  psum0 += __shfl_xor(psum0, 16);
  psum0 += __shfl_xor(psum0, 32);
  psum1 += __shfl_xor(psum1, 16);
  psum1 += __shfl_xor(psum1, 32);
  if (l < 16){
    pden_sh[row0][ksl] = psum0;
    pden_sh[row1][ksl] = psum1;
  }
  __syncthreads();
  const size_t pb = ((size_t)v*KS + ksid)*(N/M2) + blockIdx.x;
  float* pa = pacc + pb*(M2*H);
  #pragma unroll
  for (int rt=0; rt<4; rt++){
    #pragma unroll
    for (int reg=0; reg<4; reg++){
      const int row = rt*16 + quad*4 + reg;
      pa[row*H + col] = acc[rt][reg];
    }
  }
  if (t < M2){
    float den = pden_sh[t][0] + pden_sh[t][1] + pden_sh[t][2] + pden_sh[t][3];
    pdenG[pb*M2 + t] = den;
  }
  // init classifier output to bias (runs long before k3's atomics; stream-ordered)
  if (blockIdx.y == 0 && blockIdx.z == 0){
    const int idx = blockIdx.x * 512 + t;
    if (idx < N*C) outg[idx] = mm_b[idx % C];
  }
}

// ---------------- K3: combine+epilogue, MFMA QKV, VALU attention, MFMA fc, ----------------
// fused classifier: per-block partial out[n,c] via shfl-reduce + atomicAdd (K4 removed).
__global__ __launch_bounds__(256) void k3_sgfe(
    const float* __restrict__ pacc, const float* __restrict__ pdenG,
    const float* __restrict__ mlp_out,
    const float* __restrict__ gac_b, const float* __restrict__ mlp_b,
    const unsigned short* __restrict__ wq4T,
    const float* __restrict__ qb, const float* __restrict__ kb,
    const float* __restrict__ vb, const float* __restrict__ fcb,
    const float* __restrict__ confw, const float* __restrict__ confb,
    const float* __restrict__ mm_w, float* __restrict__ outg)
{
  const int v = blockIdx.y;
  const int n0 = blockIdx.x * 16;
  const int t = threadIdx.x;
  const int w = t >> 6, l = t & 63;
  const int c16 = l & 15, quad = l >> 4;
  __shared__ __align__(16) unsigned short Ffrag[4][64][8];   // feat A-fragments
  __shared__ __align__(16) unsigned short Gfrag[4][64][8];   // agg A-fragments
  __shared__ float Qs[16][H];
  __shared__ float2 KVs[16][H];
  __shared__ float pc[16][4];
  __shared__ float confs[16];

  // ---- fused split-K combine + GAC epilogue -> bf16 F fragments ----
  {
    const int col = t & 127, rh = t >> 7;
    const int bx2 = blockIdx.x >> 2;
    const int lr0 = (blockIdx.x & 3) * 16;
    const float gbv = gac_b[v*H + col];
    const float mbv = mlp_b[v*H + col];
    const int ks = col >> 5, q2 = (col & 31) >> 3, j = col & 7;
    #pragma unroll
    for (int i=0;i<8;i++){
      const int r = rh*8 + i;
      float num = 0.f, den = 0.f;
      #pragma unroll
      for (int s=0;s<KS;s++){
        const size_t pb = ((size_t)v*KS + s)*(N/M2) + bx2;
        num += pacc[pb*(M2*H) + (size_t)(lr0+r)*H + col];
        den += pdenG[pb*M2 + lr0 + r];
      }
      float x = num/den + gbv;
      x = (x >= 0.f) ? x : 0.25f*x;
      x += mlp_out[((size_t)v*N + n0 + r)*H + col] + mbv;
      Ffrag[ks][r + 16*q2][j] = f2bf(x);
    }
  }
  __syncthreads();
  // ---- QKV MFMA: wave w covers col-tiles {2w, 2w+1} for q,k,v ----
  const int colw0 = 2*w*16 + c16;
  const float QSC = 0.08838834764831845f * LOG2E;  // (1/sqrt(128)) * log2(e)
  {
    const unsigned short* bq = wq4T + (((size_t)0*V + v)*H + colw0)*H + quad*8;
    const unsigned short* bk = wq4T + (((size_t)1*V + v)*H + colw0)*H + quad*8;
    const unsigned short* bv = wq4T + (((size_t)2*V + v)*H + colw0)*H + quad*8;
    floatx4 aq[2], ak[2], av[2];
    #pragma unroll
    for (int c=0;c<2;c++){ aq[c]=(floatx4){0,0,0,0}; ak[c]=(floatx4){0,0,0,0}; av[c]=(floatx4){0,0,0,0}; }
    #pragma unroll
    for (int ks=0; ks<4; ks++){
      short8 a8 = *(const short8*)&Ffrag[ks][l][0];
      #pragma unroll
      for (int c=0;c<2;c++){
        short8 q8 = *(const short8*)(bq + (size_t)c*16*H + ks*32);
        short8 k8 = *(const short8*)(bk + (size_t)c*16*H + ks*32);
        short8 v8 = *(const short8*)(bv + (size_t)c*16*H + ks*32);
        aq[c] = __builtin_amdgcn_mfma_f32_16x16x32_bf16(a8, q8, aq[c], 0,0,0);
        ak[c] = __builtin_amdgcn_mfma_f32_16x16x32_bf16(a8, k8, ak[c], 0,0,0);
        av[c] = __builtin_amdgcn_mfma_f32_16x16x32_bf16(a8, v8, av[c], 0,0,0);
      }
    }
    #pragma unroll
    for (int c=0;c<2;c++){
      const int col = colw0 + c*16;
      const float qbv = qb[v*H+col], kbv = kb[v*H+col], vbv = vb[v*H+col];
      #pragma unroll
      for (int reg=0;reg<4;reg++){
        const int node = quad*4 + reg;
        Qs[node][col] = (aq[c][reg] + qbv) * QSC;
        KVs[node][col] = make_float2(ak[c][reg] + kbv, av[c][reg] + vbv);
      }
    }
  }
  __syncthreads();
  // ---- attention (VALU): wave w -> nodes 4w..4w+3; lane covers dims l, l+64 ----
  #pragma unroll
  for (int p=0;p<4;p++){
    const int r = 4*w + p;
    const float qa  = Qs[r][l];
    const float qb2 = Qs[r][l+64];
    float sA=0.f, aA=0.f, sB=0.f, aB=0.f;
    const float4* kvp = (const float4*)&KVs[r][0];
    #pragma unroll 4
    for (int oo=0; oo<H/2; oo++){
      float4 kv2 = kvp[oo];
      float eA0 = exp2f(qa*kv2.x);  sA += eA0; aA = fmaf(eA0, kv2.y, aA);
      float eA1 = exp2f(qa*kv2.z);  sA += eA1; aA = fmaf(eA1, kv2.w, aA);
      float eB0 = exp2f(qb2*kv2.x); sB += eB0; aB = fmaf(eB0, kv2.y, aB);
      float eB1 = exp2f(qb2*kv2.z); sB += eB1; aB = fmaf(eB1, kv2.w, aB);
    }
    // write agg into fc A-fragments (dims l and l+64)
    Gfrag[l>>5][r + 16*((l&31)>>3)][l&7] = f2bf(aA/sA);
    Gfrag[2 + (l>>5)][r + 16*((l&31)>>3)][l&7] = f2bf(aB/sB);
  }
  __syncthreads();
  // ---- fc MFMA + relu + conf gate ----
  const unsigned short* bf = wq4T + (((size_t)3*V + v)*H + colw0)*H + quad*8;
  floatx4 af[2];
  af[0]=(floatx4){0,0,0,0}; af[1]=(floatx4){0,0,0,0};
  #pragma unroll
  for (int ks=0; ks<4; ks++){
    short8 a8 = *(const short8*)&Gfrag[ks][l][0];
    #pragma unroll
    for (int c=0;c<2;c++){
      short8 b8 = *(const short8*)(bf + (size_t)c*16*H + ks*32);
      af[c] = __builtin_amdgcn_mfma_f32_16x16x32_bf16(a8, b8, af[c], 0,0,0);
    }
  }
  float g[2][4];
  float pn[4] = {0.f,0.f,0.f,0.f};
  #pragma unroll
  for (int c=0;c<2;c++){
    const int col = colw0 + c*16;
    const float fcbv = fcb[v*H+col];
    const float cwv  = confw[v*H+col];
    #pragma unroll
    for (int reg=0;reg<4;reg++){
      float gg = fmaxf(af[c][reg] + fcbv, 0.f);
      g[c][reg] = gg;
      pn[reg] += gg*cwv;
    }
  }
  #pragma unroll
  for (int reg=0;reg<4;reg++){
    pn[reg] += __shfl_xor(pn[reg], 1);
    pn[reg] += __shfl_xor(pn[reg], 2);
    pn[reg] += __shfl_xor(pn[reg], 4);
    pn[reg] += __shfl_xor(pn[reg], 8);
  }
  if (c16 == 0){
    #pragma unroll
    for (int reg=0;reg<4;reg++) pc[quad*4 + reg][w] = pn[reg];
  }
  __syncthreads();
  if (t < 16) confs[t] = pc[t][0] + pc[t][1] + pc[t][2] + pc[t][3] + confb[v];
  __syncthreads();
  // ---- fused classifier: out[n,cls] += sum_col (g*conf) * mm_w[v*H+col, cls] ----
  float pcls[4][C];
  #pragma unroll
  for (int reg=0;reg<4;reg++)
    #pragma unroll
    for (int cc=0;cc<C;cc++) pcls[reg][cc] = 0.f;
  #pragma unroll
  for (int c=0;c<2;c++){
    const int col = colw0 + c*16;
    const float* mwp = mm_w + (size_t)(v*H + col)*C;
    #pragma unroll
    for (int reg=0;reg<4;reg++){
      const float val = g[c][reg]*confs[quad*4 + reg];
      #pragma unroll
      for (int cc=0;cc<C;cc++) pcls[reg][cc] = fmaf(val, mwp[cc], pcls[reg][cc]);
    }
  }
  #pragma unroll
  for (int reg=0;reg<4;reg++)
    #pragma unroll
    for (int cc=0;cc<C;cc++){
      float x = pcls[reg][cc];
      x += __shfl_xor(x,1); x += __shfl_xor(x,2);
      x += __shfl_xor(x,4); x += __shfl_xor(x,8);
      if (c16 == 0)
        atomicAdd(&outg[(size_t)(n0 + quad*4 + reg)*C + cc], x);
    }
}

extern "C" void kernel_launch(void* const* d_in, const int* in_sizes, int n_in,
                              void* d_out, int out_size, void* d_ws, size_t ws_size,
                              hipStream_t stream)
{
  (void)in_sizes; (void)n_in; (void)out_size; (void)ws_size;
  const float* data  = (const float*)d_in[0];
  const int*   adj   = (const int*)d_in[1];
  const float* gac_w = (const float*)d_in[2];
  const float* gac_b = (const float*)d_in[3];
  const float* a1    = (const float*)d_in[4];
  const float* a2    = (const float*)d_in[5];
  const float* mlp_w = (const float*)d_in[6];
  const float* mlp_b = (const float*)d_in[7];
  const float* q_w   = (const float*)d_in[8];
  const float* q_b   = (const float*)d_in[9];
  const float* k_w   = (const float*)d_in[10];
  const float* k_b   = (const float*)d_in[11];
  const float* v_w   = (const float*)d_in[12];
  const float* v_b   = (const float*)d_in[13];
  const float* fc_w  = (const float*)d_in[14];
  const float* fc_b  = (const float*)d_in[15];
  const float* cw    = (const float*)d_in[16];
  const float* cb    = (const float*)d_in[17];
  const float* mm_w  = (const float*)d_in[18];
  const float* mm_b  = (const float*)d_in[19];

  float* ws = (float*)d_ws;
  const size_t VNH = (size_t)V*N*H;
  float* mlp   = ws;
  float* e1    = ws + VNH;
  float* e2    = e1 + (size_t)V*N;
  unsigned short* hT   = (unsigned short*)(e2 + (size_t)V*N); // [V][H][N] bf16
  unsigned short* wT   = hT + VNH;                            // [2][V][H][D] bf16
  unsigned short* wq4T = wT + (size_t)2*V*H*D;                // [4][V][H][H] bf16
  float* pacc  = (float*)(wq4T + (size_t)4*V*H*H);            // [V][KS][N/M2][M2][H]
  float* pden  = pacc + (size_t)V*KS*(N/M2)*M2*H;             // [V][KS][N/M2][M2]

  k0_all <<<dim3(72),          256, 0, stream>>>(gac_w, mlp_w, q_w, k_w, v_w, fc_w, wT, wq4T);
  k1_gemm<<<dim3(N/M1, V),     512, 0, stream>>>(data, wT, a1, a2, hT, mlp, e1, e2);
  k2_attn<<<dim3(N/M2, KS, V), 512, 0, stream>>>(hT, adj, e1, e2, pacc, pden,
                                                 mm_b, (float*)d_out);
  k3_sgfe<<<dim3(N/16, V),     256, 0, stream>>>(pacc, pden, mlp, gac_b, mlp_b,
                                                 wq4T, q_b, k_b, v_b, fc_b,
                                                 cw, cb, mm_w, (float*)d_out);
}